// Round 1
// baseline (1990.805 us; speedup 1.0000x reference)
//
#include <hip/hip_runtime.h>
#include <hip/hip_bf16.h>
#include <math.h>

// Problem constants (from reference): N_IN=32, N_OUT=31, H=128, B1*B2=65536 points.
#define NPTS_DEFAULT 65536

// ws layout (floats):
//   W0T [32][128]   @ 0       (W0T[c][j] = W0[j][c])
//   W1T [128][128]  @ 4096    (W1T[k][j] = W1[j][k])
//   W2T [128][128]  @ 20480
//   W3T [128][31]   @ 36864   (W3T[k][o] = W3[o][k])
// total 40832 floats = 163328 B
#define WS_FLOATS 40832

__global__ void transpose_weights(const float* __restrict__ W0,
                                  const float* __restrict__ W1,
                                  const float* __restrict__ W2,
                                  const float* __restrict__ W3,
                                  float* __restrict__ ws) {
    int idx = blockIdx.x * blockDim.x + threadIdx.x;
    if (idx < 4096) {
        int c = idx >> 7, j = idx & 127;
        ws[idx] = W0[j * 32 + c];
    } else if (idx < 20480) {
        int t = idx - 4096; int k = t >> 7, j = t & 127;
        ws[4096 + k * 128 + j] = W1[j * 128 + k];
    } else if (idx < 36864) {
        int t = idx - 20480; int k = t >> 7, j = t & 127;
        ws[20480 + k * 128 + j] = W2[j * 128 + k];
    } else if (idx < WS_FLOATS) {
        int t = idx - 36864; int k = t / 31, o = t - k * 31;
        ws[36864 + k * 31 + o] = W3[o * 128 + k];
    }
}

__device__ __forceinline__ float fast_tanh(float z) {
    // tanh(z) = 1 - 2/(exp(2z)+1); exp via v_exp_f32, rcp via v_rcp_f32.
    float e = __expf(2.0f * z);
    return 1.0f - 2.0f * __builtin_amdgcn_rcpf(e + 1.0f);
}

// TR=true: weights are pre-transposed (coalesced reads). TR=false: raw layout fallback.
template <bool TR>
__global__ void __launch_bounds__(128, 2)
node_fused(const float* __restrict__ tptr,
           const float* __restrict__ y,
           const float* __restrict__ P0, const float* __restrict__ b0,
           const float* __restrict__ P1, const float* __restrict__ b1,
           const float* __restrict__ P2, const float* __restrict__ b2,
           const float* __restrict__ P3, const float* __restrict__ b3,
           float* __restrict__ out, float* __restrict__ jac) {
    // X stride 36 floats: rows 16B-aligned (36%4==0), lane-write stride 36 words.
    __shared__ float Xs_all[2][128 * 36];

    const int wave = threadIdx.x >> 6;
    const int lane = threadIdx.x & 63;
    float* Xs = Xs_all[wave];
    const int p = blockIdx.x * 2 + wave;
    const int j = lane;  // this lane owns hidden rows j and j+64

    // ---- per-lane input element; x[0..30]=y[p], x[31]=sin(t) ----
    float xv = 0.0f;
    if (lane < 31)       xv = y[(size_t)p * 31 + lane];
    else if (lane == 31) xv = sinf(tptr[0]);

    // weight accessors
    auto w0 = [&](int c, int jj) -> float {
        return TR ? P0[c * 128 + jj] : P0[jj * 32 + c];
    };
    auto w3 = [&](int k, int o) -> float {
        return TR ? P3[k * 31 + o] : P3[o * 128 + k];
    };

    // ---- layer 0 forward: z0 = W0 @ x ----
    float za = 0.0f, zb = 0.0f;
    #pragma unroll
    for (int c = 0; c < 32; ++c) {
        float xc = __shfl(xv, c, 64);
        za = fmaf(w0(c, j), xc, za);
        zb = fmaf(w0(c, j + 64), xc, zb);
    }
    float h0a = fast_tanh(za + b0[j]);
    float h0b = fast_tanh(zb + b0[j + 64]);
    float d0a = 1.0f - h0a * h0a;
    float d0b = 1.0f - h0b * h0b;

    // ---- build X0 = [ D0*W0[:,:31] | h0 ] in LDS ----
    #pragma unroll
    for (int c = 0; c < 31; ++c) {
        Xs[j * 36 + c]        = d0a * w0(c, j);
        Xs[(j + 64) * 36 + c] = d0b * w0(c, j + 64);
    }
    Xs[j * 36 + 31]        = h0a;
    Xs[(j + 64) * 36 + 31] = h0b;
    __syncthreads();

    // ---- layers 1 and 2: Z = W @ X; X' = [ D*Z[:,:31] | tanh(Z[:,31]+b) ] ----
    float acc_a[32], acc_b[32];
    const float* WP = P1;
    const float* bb = b1;
    #pragma unroll 1
    for (int layer = 0; layer < 2; ++layer) {
        #pragma unroll
        for (int c = 0; c < 32; ++c) { acc_a[c] = 0.0f; acc_b[c] = 0.0f; }

        for (int k = 0; k < 128; ++k) {
            float wa = TR ? WP[k * 128 + j]      : WP[j * 128 + k];
            float wb = TR ? WP[k * 128 + j + 64] : WP[(j + 64) * 128 + k];
            const float4* Xrow = reinterpret_cast<const float4*>(&Xs[k * 36]);
            #pragma unroll
            for (int q = 0; q < 8; ++q) {
                float4 xq = Xrow[q];  // wave-uniform address -> LDS broadcast
                acc_a[4 * q + 0] = fmaf(wa, xq.x, acc_a[4 * q + 0]);
                acc_a[4 * q + 1] = fmaf(wa, xq.y, acc_a[4 * q + 1]);
                acc_a[4 * q + 2] = fmaf(wa, xq.z, acc_a[4 * q + 2]);
                acc_a[4 * q + 3] = fmaf(wa, xq.w, acc_a[4 * q + 3]);
                acc_b[4 * q + 0] = fmaf(wb, xq.x, acc_b[4 * q + 0]);
                acc_b[4 * q + 1] = fmaf(wb, xq.y, acc_b[4 * q + 1]);
                acc_b[4 * q + 2] = fmaf(wb, xq.z, acc_b[4 * q + 2]);
                acc_b[4 * q + 3] = fmaf(wb, xq.w, acc_b[4 * q + 3]);
            }
        }

        float ha = fast_tanh(acc_a[31] + bb[j]);
        float hb = fast_tanh(acc_b[31] + bb[j + 64]);
        float da = 1.0f - ha * ha;
        float db = 1.0f - hb * hb;

        __syncthreads();  // all reads of old X complete
        #pragma unroll
        for (int c = 0; c < 31; ++c) {
            Xs[j * 36 + c]        = da * acc_a[c];
            Xs[(j + 64) * 36 + c] = db * acc_b[c];
        }
        Xs[j * 36 + 31]        = ha;
        Xs[(j + 64) * 36 + 31] = hb;
        __syncthreads();

        WP = P2; bb = b2;
    }

    // ---- layer 3: Y3 = W3 @ X2 ; out = Y3[:,31]+b3, jac = Y3[:,:31] ----
    if (lane < 31) {
        const int o = lane;
        float acc[32];
        #pragma unroll
        for (int c = 0; c < 32; ++c) acc[c] = 0.0f;

        for (int k = 0; k < 128; ++k) {
            float w = w3(k, o);
            const float4* Xrow = reinterpret_cast<const float4*>(&Xs[k * 36]);
            #pragma unroll
            for (int q = 0; q < 8; ++q) {
                float4 xq = Xrow[q];
                acc[4 * q + 0] = fmaf(w, xq.x, acc[4 * q + 0]);
                acc[4 * q + 1] = fmaf(w, xq.y, acc[4 * q + 1]);
                acc[4 * q + 2] = fmaf(w, xq.z, acc[4 * q + 2]);
                acc[4 * q + 3] = fmaf(w, xq.w, acc[4 * q + 3]);
            }
        }

        out[(size_t)p * 31 + o] = acc[31] + b3[o];
        float* jr = jac + ((size_t)p * 31 + o) * 31;
        #pragma unroll
        for (int c = 0; c < 31; ++c) jr[c] = acc[c];
    }
}

extern "C" void kernel_launch(void* const* d_in, const int* in_sizes, int n_in,
                              void* d_out, int out_size, void* d_ws, size_t ws_size,
                              hipStream_t stream) {
    const float* t  = (const float*)d_in[0];
    const float* y  = (const float*)d_in[1];
    const float* W0 = (const float*)d_in[2];
    const float* b0 = (const float*)d_in[3];
    const float* W1 = (const float*)d_in[4];
    const float* b1 = (const float*)d_in[5];
    const float* W2 = (const float*)d_in[6];
    const float* b2 = (const float*)d_in[7];
    const float* W3 = (const float*)d_in[8];
    const float* b3 = (const float*)d_in[9];

    const int npts = in_sizes[1] / 31;  // 65536
    float* out = (float*)d_out;
    float* jac = out + (size_t)npts * 31;

    const bool use_ws = ws_size >= (size_t)WS_FLOATS * sizeof(float);

    if (use_ws) {
        float* ws = (float*)d_ws;
        transpose_weights<<<(WS_FLOATS + 255) / 256, 256, 0, stream>>>(W0, W1, W2, W3, ws);
        node_fused<true><<<npts / 2, 128, 0, stream>>>(
            t, y, ws, b0, ws + 4096, b1, ws + 20480, b2, ws + 36864, b3, out, jac);
    } else {
        node_fused<false><<<npts / 2, 128, 0, stream>>>(
            t, y, W0, b0, W1, b1, W2, b2, W3, b3, out, jac);
    }
}

// Round 2
// 385.773 us; speedup vs baseline: 5.1606x; 5.1606x over previous
//
#include <hip/hip_runtime.h>
#include <hip/hip_bf16.h>
#include <math.h>

// N_IN=32, N_OUT=31, H=128, npts=65536.
// Per point: X_l (128x32) propagated through Z = W_l @ X, with
// X'[:, :31] = D * Z[:, :31], X'[:, 31] = tanh(Z[:,31] + b).
// MFMA 16x16x32 bf16; wave w owns rows [16w, 16w+16) of every layer.

using short8 = __attribute__((ext_vector_type(8))) short;
using f32x4  = __attribute__((ext_vector_type(4))) float;

#define WAVES 8
#define PB 4          // points per pass
#define PPB 32        // points per block
#define STRIDE 136    // ushort elems per XT row (272 B: 16B-aligned, 2-way banks)

__device__ __forceinline__ float fast_tanh(float z) {
    float e = __expf(2.0f * z);
    return 1.0f - 2.0f * __builtin_amdgcn_rcpf(e + 1.0f);
}

__device__ __forceinline__ ushort f2bf(float f) {
    union { float f; unsigned u; } v; v.f = f;
    unsigned r = v.u + 0x7fffu + ((v.u >> 16) & 1u);
    return (ushort)(r >> 16);
}

__device__ __forceinline__ short8 pack8(const float* s) {
    union { ushort u[8]; short8 v; } r;
    #pragma unroll
    for (int i = 0; i < 8; ++i) r.u[i] = f2bf(s[i]);
    return r.v;
}

__global__ void __launch_bounds__(512, 4)
node_mfma(const float* __restrict__ tptr,
          const float* __restrict__ y,
          const float* __restrict__ W0, const float* __restrict__ b0,
          const float* __restrict__ W1, const float* __restrict__ b1,
          const float* __restrict__ W2, const float* __restrict__ b2,
          const float* __restrict__ W3, const float* __restrict__ b3,
          float* __restrict__ out, float* __restrict__ jac, int npts) {
    __shared__ ushort XT[PB][32][STRIDE];  // X^T per point: [col c][row j]
    __shared__ float  xb[PB][32];

    const int tid  = threadIdx.x;
    const int w    = tid >> 6;
    const int lane = tid & 63;
    const int r16  = lane & 15;   // A-row / B-col / D-col within tile
    const int g    = lane >> 4;   // k-octet group; D rows = 4g..4g+3
    const int j    = 16 * w + r16;  // this wave's m-tile rows

    // ---- weights -> registers ----
    float w0f[8];   // W0[j][g*8+i] as f32 (layer-0 VALU dot + X0 build)
    {
        const float4* p4 = reinterpret_cast<const float4*>(W0 + j * 32 + g * 8);
        float4 q0 = p4[0], q1 = p4[1];
        w0f[0]=q0.x; w0f[1]=q0.y; w0f[2]=q0.z; w0f[3]=q0.w;
        w0f[4]=q1.x; w0f[5]=q1.y; w0f[6]=q1.z; w0f[7]=q1.w;
    }
    short8 aW[2][4];  // A-frags W1, W2: lane holds row j, k = kc*32 + g*8 + i
    #pragma unroll
    for (int L = 0; L < 2; ++L) {
        const float* WL = L ? W2 : W1;
        #pragma unroll
        for (int kc = 0; kc < 4; ++kc) {
            float tmp[8];
            const float4* p4 = reinterpret_cast<const float4*>(WL + j * 128 + kc * 32 + g * 8);
            float4 q0 = p4[0], q1 = p4[1];
            tmp[0]=q0.x; tmp[1]=q0.y; tmp[2]=q0.z; tmp[3]=q0.w;
            tmp[4]=q1.x; tmp[5]=q1.y; tmp[6]=q1.z; tmp[7]=q1.w;
            aW[L][kc] = pack8(tmp);
        }
    }
    // layer 3: padded to 32 rows; wave w does (m=(w>>1)&1, n=w&1) for 2 points
    const int mw = (w >> 1) & 1, nw = w & 1;
    const int r3 = 16 * mw + r16;
    short8 aW3[4];
    #pragma unroll
    for (int kc = 0; kc < 4; ++kc) {
        float tmp[8];
        if (r3 < 31) {
            const float4* p4 = reinterpret_cast<const float4*>(W3 + r3 * 128 + kc * 32 + g * 8);
            float4 q0 = p4[0], q1 = p4[1];
            tmp[0]=q0.x; tmp[1]=q0.y; tmp[2]=q0.z; tmp[3]=q0.w;
            tmp[4]=q1.x; tmp[5]=q1.y; tmp[6]=q1.z; tmp[7]=q1.w;
        } else {
            #pragma unroll
            for (int i = 0; i < 8; ++i) tmp[i] = 0.0f;
        }
        aW3[kc] = pack8(tmp);
    }
    const float b0v = b0[j];
    float bv[2][4], b3v[4];
    #pragma unroll
    for (int reg = 0; reg < 4; ++reg) {
        bv[0][reg] = b1[16 * w + 4 * g + reg];
        bv[1][reg] = b2[16 * w + 4 * g + reg];
        int o = 16 * mw + 4 * g + reg;
        b3v[reg] = (o < 31) ? b3[o] : 0.0f;
    }
    const float force = sinf(tptr[0]);

    for (int pass = 0; pass < PPB / PB; ++pass) {
        const int pbase = blockIdx.x * PPB + pass * PB;

        // ---- stage x ----
        if (tid < PB * 32) {
            int pl = tid >> 5, c = tid & 31;
            float v = 0.0f;
            if (pbase + pl < npts) v = (c < 31) ? y[(size_t)(pbase + pl) * 31 + c] : force;
            xb[pl][c] = v;
        }
        __syncthreads();

        // ---- layer 0: X0 = [D0*W0[:,:31] | h0] -> XT ----
        #pragma unroll
        for (int pl = 0; pl < PB; ++pl) {
            float zp = 0.0f;
            #pragma unroll
            for (int i = 0; i < 8; ++i) zp = fmaf(w0f[i], xb[pl][g * 8 + i], zp);
            zp += __shfl_xor(zp, 16, 64);
            zp += __shfl_xor(zp, 32, 64);
            float h = fast_tanh(zp + b0v);
            float d = 1.0f - h * h;
            #pragma unroll
            for (int i = 0; i < 8; ++i) {
                int c = g * 8 + i;
                XT[pl][c][j] = f2bf((c == 31) ? h : d * w0f[i]);
            }
        }
        __syncthreads();

        // ---- layers 1, 2 ----
        #pragma unroll
        for (int L = 0; L < 2; ++L) {
            uint2 stashA[PB], stashB[PB];
            #pragma unroll
            for (int pl = 0; pl < PB; ++pl) {
                f32x4 a0 = {0.f, 0.f, 0.f, 0.f}, a1 = {0.f, 0.f, 0.f, 0.f};
                #pragma unroll
                for (int kc = 0; kc < 4; ++kc) {
                    short8 bf0 = *reinterpret_cast<const short8*>(&XT[pl][r16][kc * 32 + g * 8]);
                    short8 bf1 = *reinterpret_cast<const short8*>(&XT[pl][16 + r16][kc * 32 + g * 8]);
                    a0 = __builtin_amdgcn_mfma_f32_16x16x32_bf16(aW[L][kc], bf0, a0, 0, 0, 0);
                    a1 = __builtin_amdgcn_mfma_f32_16x16x32_bf16(aW[L][kc], bf1, a1, 0, 0, 0);
                }
                union { ushort u[4]; uint2 v; } pa, pb;
                #pragma unroll
                for (int reg = 0; reg < 4; ++reg) {
                    float tv = fast_tanh(a1[reg] + bv[L][reg]);
                    float d  = 1.0f - tv * tv;
                    float dd = __shfl(d, lane | 15, 64);
                    pa.u[reg] = f2bf(dd * a0[reg]);
                    pb.u[reg] = (r16 == 15) ? f2bf(tv) : f2bf(dd * a1[reg]);
                }
                stashA[pl] = pa.v; stashB[pl] = pb.v;
            }
            __syncthreads();  // all reads of XT done
            #pragma unroll
            for (int pl = 0; pl < PB; ++pl) {
                *reinterpret_cast<uint2*>(&XT[pl][r16][16 * w + 4 * g])      = stashA[pl];
                *reinterpret_cast<uint2*>(&XT[pl][16 + r16][16 * w + 4 * g]) = stashB[pl];
            }
            __syncthreads();
        }

        // ---- layer 3: Y = W3pad @ X2 ; scatter out/jac ----
        #pragma unroll
        for (int tsk = 0; tsk < 2; ++tsk) {
            int pl = (w >> 2) + tsk * 2;
            f32x4 a = {0.f, 0.f, 0.f, 0.f};
            #pragma unroll
            for (int kc = 0; kc < 4; ++kc) {
                short8 bf = *reinterpret_cast<const short8*>(&XT[pl][16 * nw + r16][kc * 32 + g * 8]);
                a = __builtin_amdgcn_mfma_f32_16x16x32_bf16(aW3[kc], bf, a, 0, 0, 0);
            }
            size_t p = (size_t)(pbase + pl);
            int c = 16 * nw + r16;
            if ((int)p < npts) {
                #pragma unroll
                for (int reg = 0; reg < 4; ++reg) {
                    int o = 16 * mw + 4 * g + reg;
                    if (o < 31) {
                        if (c == 31) out[p * 31 + o] = a[reg] + b3v[reg];
                        else         jac[(p * 31 + o) * 31 + c] = a[reg];
                    }
                }
            }
        }
        __syncthreads();  // XT reused next pass
    }
}

extern "C" void kernel_launch(void* const* d_in, const int* in_sizes, int n_in,
                              void* d_out, int out_size, void* d_ws, size_t ws_size,
                              hipStream_t stream) {
    const float* t  = (const float*)d_in[0];
    const float* y  = (const float*)d_in[1];
    const float* W0 = (const float*)d_in[2];
    const float* b0 = (const float*)d_in[3];
    const float* W1 = (const float*)d_in[4];
    const float* b1 = (const float*)d_in[5];
    const float* W2 = (const float*)d_in[6];
    const float* b2 = (const float*)d_in[7];
    const float* W3 = (const float*)d_in[8];
    const float* b3 = (const float*)d_in[9];

    const int npts = in_sizes[1] / 31;  // 65536
    float* out = (float*)d_out;
    float* jac = out + (size_t)npts * 31;

    const int blocks = (npts + PPB - 1) / PPB;  // 2048
    node_mfma<<<blocks, 512, 0, stream>>>(t, y, W0, b0, W1, b1, W2, b2, W3, b3,
                                          out, jac, npts);
}